// Round 8
// baseline (678.117 us; speedup 1.0000x reference)
//
#include <hip/hip_runtime.h>
#include <hip/hip_bf16.h>
#include <math.h>

typedef short short8 __attribute__((ext_vector_type(8)));
typedef float f32x16 __attribute__((ext_vector_type(16)));

#define B_ROWS 8192
#define IN_DIM 1024
#define OUT_DIM 256
#define M_DIM 1280
#define P_DIM 2304
#define RB 32                 // batch rows per block
#define NJ 10                 // 1280 / 128

#define HS 1288               // H panel row stride (shorts): 2576 B, 4-bank step/row
#define LWS 132               // LW row stride (f32): 528 B
#define TS 136                // stage row stride (shorts): 272 B

// ws layout: Xbf bf16[8192][1024], Wbf bf16[1280][2304]
#define WBF_OFF (B_ROWS * (size_t)IN_DIM * 2)   // 16,777,216 B; total 22,675,456 B

__device__ __forceinline__ short f2bf(float x)
{
    __hip_bfloat16 h = __float2bfloat16(x);
    return *(short*)&h;
}

// fast tanh: (e^{2x}-1)/(e^{2x}+1), hw exp + hw rcp. |err| ~1e-6.
__device__ __forceinline__ float tanh_fast(float x)
{
    x = fminf(fmaxf(x, -15.f), 15.f);
    float e = __expf(2.f * x);
    return (e - 1.f) * __builtin_amdgcn_rcpf(e + 1.f);
}

__global__ __launch_bounds__(256)
void convert_x(const float* __restrict__ x, short* __restrict__ Xbf)
{
    int idx = blockIdx.x * 256 + threadIdx.x;     // 8192*1024/8 threads
    int r  = idx >> 7;
    int c8 = (idx & 127) << 3;
    const float* src = x + (size_t)r * IN_DIM + c8;
    float4 a0 = *(const float4*)src;
    float4 a1 = *(const float4*)(src + 4);
    short8 s;
    s[0] = f2bf(a0.x); s[1] = f2bf(a0.y); s[2] = f2bf(a0.z); s[3] = f2bf(a0.w);
    s[4] = f2bf(a1.x); s[5] = f2bf(a1.y); s[6] = f2bf(a1.z); s[7] = f2bf(a1.w);
    *(short8*)(Xbf + (size_t)r * IN_DIM + c8) = s;
}

__global__ __launch_bounds__(256)
void convert_w(const float* __restrict__ W, short* __restrict__ Wbf)
{
    size_t e8 = ((size_t)blockIdx.x * 256 + threadIdx.x) * 8;  // flat, exact multiple
    float4 a0 = *(const float4*)(W + e8);
    float4 a1 = *(const float4*)(W + e8 + 4);
    short8 s;
    s[0] = f2bf(a0.x); s[1] = f2bf(a0.y); s[2] = f2bf(a0.z); s[3] = f2bf(a0.w);
    s[4] = f2bf(a1.x); s[5] = f2bf(a1.y); s[6] = f2bf(a1.z); s[7] = f2bf(a1.w);
    *(short8*)(Wbf + e8) = s;
}

// One block = 32 batch rows, 256 threads (4 waves), full private J-loop.
// LDS: H panel (bf16 h-history, resident) + union{GEMM stages + PreL | LW f32}.
__global__ __launch_bounds__(256, 1)
void fused(const short* __restrict__ Xbf, const short* __restrict__ Wbf,
           const float* __restrict__ Wf, const float* __restrict__ bias,
           float* __restrict__ out)
{
    __shared__ __align__(16) short Hs[RB * HS];          // 82,432 B
    __shared__ __align__(16) char  Ub[128 * LWS * 4];    // 67,584 B union
    __shared__ float hb[2][RB];

    short* xs   = (short*)Ub;                 // [RB][TS]   8,704 B
    short* Wst  = (short*)(Ub + RB * TS * 2); // [128][TS] 34,816 B (ends 43,520)
    float* PreL = (float*)(Ub + 43520);       // [RB][LWS] 16,896 B (ends 60,416)
    float* lwf  = (float*)Ub;                 // [128][LWS] (seq phase only)

    const int tid = threadIdx.x;
    const int lane = tid & 63;
    const int w   = tid >> 6;        // wave 0..3
    const int rl  = lane & 31;       // row within block / frag row-col
    const int hf  = lane >> 5;       // half 0/1
    const int u_lo = w * 32 + hf * 16;   // this lane-slot's u-slice base
    const int bm  = blockIdx.x * RB;

#pragma unroll 1
    for (int J = 0; J < NJ; ++J) {
        const int j0 = J * 128;
        f32x16 acc;
#pragma unroll
        for (int r = 0; r < 16; ++r) acc[r] = 0.f;

        __syncthreads();   // previous J's seq (LW reads / H writes) fully done

        // ---- phase 1: k in [0, IN_DIM), A from Xbf via LDS stage ----------
#pragma unroll 1
        for (int k0 = 0; k0 < IN_DIM; k0 += 128) {
#pragma unroll
            for (int c = 0; c < 2; ++c) {              // x tile 32x128 bf16
                int idx = tid + c * 256;
                int r = idx >> 4, k8 = (idx & 15) << 3;
                *(short8*)&xs[r * TS + k8] =
                    *(const short8*)(Xbf + (size_t)(bm + r) * IN_DIM + k0 + k8);
            }
#pragma unroll
            for (int c = 0; c < 8; ++c) {              // W tile 128x128 bf16
                int idx = tid + c * 256;
                int n = idx >> 4, k8 = (idx & 15) << 3;
                *(short8*)&Wst[n * TS + k8] =
                    *(const short8*)(Wbf + (size_t)(j0 + n) * P_DIM + k0 + k8);
            }
            __syncthreads();
#pragma unroll
            for (int k16 = 0; k16 < 8; ++k16) {
                short8 a = *(const short8*)&xs[rl * TS + k16 * 16 + hf * 8];
                short8 b = *(const short8*)&Wst[(w * 32 + rl) * TS + k16 * 16 + hf * 8];
                acc = __builtin_amdgcn_mfma_f32_32x32x16_bf16(a, b, acc, 0, 0, 0);
            }
            __syncthreads();
        }

        // ---- phase 2: k in [IN_DIM, IN_DIM+j0), A direct from H panel -----
#pragma unroll 1
        for (int k0 = 0; k0 < j0; k0 += 128) {
#pragma unroll
            for (int c = 0; c < 8; ++c) {
                int idx = tid + c * 256;
                int n = idx >> 4, k8 = (idx & 15) << 3;
                *(short8*)&Wst[n * TS + k8] =
                    *(const short8*)(Wbf + (size_t)(j0 + n) * P_DIM + IN_DIM + k0 + k8);
            }
            __syncthreads();
#pragma unroll
            for (int k16 = 0; k16 < 8; ++k16) {
                short8 a = *(const short8*)&Hs[rl * HS + k0 + k16 * 16 + hf * 8];
                short8 b = *(const short8*)&Wst[(w * 32 + rl) * TS + k16 * 16 + hf * 8];
                acc = __builtin_amdgcn_mfma_f32_32x32x16_bf16(a, b, acc, 0, 0, 0);
            }
            __syncthreads();
        }

        // ---- epilogue: PreL = acc + bias (C layout: col=lane&31, row from reg)
        {
            float bv = bias[j0 + w * 32 + rl];
#pragma unroll
            for (int r = 0; r < 16; ++r) {
                int row = (r & 3) + 8 * (r >> 2) + 4 * hf;
                PreL[row * LWS + w * 32 + rl] = acc[r] + bv;
            }
        }
        __syncthreads();

        // seq accumulators: this lane-slot's 16-u slice for its row
        float as[16];
#pragma unroll
        for (int q = 0; q < 4; ++q) {
            float4 v = *(const float4*)&PreL[rl * LWS + u_lo + q * 4];
            as[q * 4 + 0] = v.x; as[q * 4 + 1] = v.y;
            as[q * 4 + 2] = v.z; as[q * 4 + 3] = v.w;
        }
        __syncthreads();

        // ---- load LW f32 (zero for u <= t), clobbers stage/PreL region ----
        {
            int u = tid & 127, th = tid >> 7;
#pragma unroll
            for (int it = 0; it < 16; ++it) {
                int t4 = (it * 2 + th) * 4;
                float4 v = *(const float4*)(Wf + (size_t)(j0 + u) * P_DIM + IN_DIM + j0 + t4);
                lwf[(t4 + 0) * LWS + u] = (u > t4 + 0) ? v.x : 0.f;
                lwf[(t4 + 1) * LWS + u] = (u > t4 + 1) ? v.y : 0.f;
                lwf[(t4 + 2) * LWS + u] = (u > t4 + 2) ? v.z : 0.f;
                lwf[(t4 + 3) * LWS + u] = (u > t4 + 3) ? v.w : 0.f;
            }
        }
        __syncthreads();

        // ---- 128 sequential steps, 16-u slice per lane-slot ---------------
#pragma unroll 1
        for (int sg = 0; sg < 8; ++sg) {
            const bool own = (w == (sg >> 1)) && (hf == (sg & 1));
#pragma unroll
            for (int s = 0; s < 16; ++s) {
                const int t = sg * 16 + s;
                if (own) {
                    float h = tanh_fast(as[s]);
                    as[s] = h;
                    hb[t & 1][rl] = h;
                }
                __syncthreads();
                float h = hb[t & 1][rl];
                const float* wr_ = &lwf[t * LWS + u_lo];
#pragma unroll
                for (int q = 0; q < 4; ++q) {
                    float4 wv = *(const float4*)(wr_ + q * 4);
                    as[q * 4 + 0] += wv.x * h;
                    as[q * 4 + 1] += wv.y * h;
                    as[q * 4 + 2] += wv.z * h;
                    as[q * 4 + 3] += wv.w * h;
                }
            }
        }

        // ---- write h (bf16) into H panel ----------------------------------
#pragma unroll
        for (int q = 0; q < 2; ++q) {
            short8 sv;
#pragma unroll
            for (int e = 0; e < 8; ++e) sv[e] = f2bf(as[q * 8 + e]);
            *(short8*)&Hs[rl * HS + j0 + u_lo + q * 8] = sv;
        }

        // ---- output region: sigmoid(h) ------------------------------------
        if (J >= 8) {
            float* op = out + (size_t)(bm + rl) * OUT_DIM + (j0 - IN_DIM) + u_lo;
#pragma unroll
            for (int q = 0; q < 4; ++q) {
                float4 v;
                v.x = 1.f / (1.f + __expf(-as[q * 4 + 0]));
                v.y = 1.f / (1.f + __expf(-as[q * 4 + 1]));
                v.z = 1.f / (1.f + __expf(-as[q * 4 + 2]));
                v.w = 1.f / (1.f + __expf(-as[q * 4 + 3]));
                *(float4*)(op + q * 4) = v;
            }
        }
    }
}

extern "C" void kernel_launch(void* const* d_in, const int* in_sizes, int n_in,
                              void* d_out, int out_size, void* d_ws, size_t ws_size,
                              hipStream_t stream)
{
    const float* x    = (const float*)d_in[0];   // (8192, 1024)
    const float* W    = (const float*)d_in[1];   // (1280, 2304)
    const float* bias = (const float*)d_in[2];   // (1280,)
    float* out = (float*)d_out;
    short* Xbf = (short*)d_ws;
    short* Wbf = (short*)((char*)d_ws + WBF_OFF);

    convert_x<<<dim3(B_ROWS * IN_DIM / 8 / 256), dim3(256), 0, stream>>>(x, Xbf);
    convert_w<<<dim3(M_DIM * P_DIM / 8 / 256), dim3(256), 0, stream>>>(W, Wbf);
    fused<<<dim3(B_ROWS / RB), dim3(256), 0, stream>>>(Xbf, Wbf, W, bias, out);
}

// Round 9
// 666.519 us; speedup vs baseline: 1.0174x; 1.0174x over previous
//
#include <hip/hip_runtime.h>
#include <hip/hip_bf16.h>
#include <math.h>

typedef short short8 __attribute__((ext_vector_type(8)));
typedef float f32x16 __attribute__((ext_vector_type(16)));

#define B_ROWS 8192
#define IN_DIM 1024
#define OUT_DIM 256
#define M_DIM 1280
#define P_DIM 2304
#define RB 32                 // batch rows per block
#define NJ 10

#define HCOLS 1152            // H panel cols (last 128 never re-read)
#define LWR 160               // lwf row stride f32 (8 slices * 20)
#define TS 136                // GEMM stage row stride (shorts)
#define PLS 132               // PreL row stride (f32)

// ws: Xbf bf16[8192][1024], Wbf bf16[1280][2304]
#define WBF_OFF (B_ROWS * (size_t)IN_DIM * 2)

__device__ __forceinline__ short f2bf(float x)
{
    __hip_bfloat16 h = __float2bfloat16(x);
    return *(short*)&h;
}

__device__ __forceinline__ float tanh_fast(float x)
{
    x = fminf(fmaxf(x, -15.f), 15.f);
    float e = __expf(2.f * x);
    return (e - 1.f) * __builtin_amdgcn_rcpf(e + 1.f);
}

__global__ __launch_bounds__(256)
void convert_x(const float* __restrict__ x, short* __restrict__ Xbf)
{
    int idx = blockIdx.x * 256 + threadIdx.x;
    int r  = idx >> 7;
    int c8 = (idx & 127) << 3;
    const float* src = x + (size_t)r * IN_DIM + c8;
    float4 a0 = *(const float4*)src;
    float4 a1 = *(const float4*)(src + 4);
    short8 s;
    s[0] = f2bf(a0.x); s[1] = f2bf(a0.y); s[2] = f2bf(a0.z); s[3] = f2bf(a0.w);
    s[4] = f2bf(a1.x); s[5] = f2bf(a1.y); s[6] = f2bf(a1.z); s[7] = f2bf(a1.w);
    *(short8*)(Xbf + (size_t)r * IN_DIM + c8) = s;
}

__global__ __launch_bounds__(256)
void convert_w(const float* __restrict__ W, short* __restrict__ Wbf)
{
    size_t e8 = ((size_t)blockIdx.x * 256 + threadIdx.x) * 8;
    float4 a0 = *(const float4*)(W + e8);
    float4 a1 = *(const float4*)(W + e8 + 4);
    short8 s;
    s[0] = f2bf(a0.x); s[1] = f2bf(a0.y); s[2] = f2bf(a0.z); s[3] = f2bf(a0.w);
    s[4] = f2bf(a1.x); s[5] = f2bf(a1.y); s[6] = f2bf(a1.z); s[7] = f2bf(a1.w);
    *(short8*)(Wbf + e8) = s;
}

// One block = 32 rows, 256 threads. GEMM: 4 waves x 32-col tiles (32x32x16
// MFMA). Seq: each wave owns 8 rows entirely; lane = (row&7)|(slice<<3),
// slice = 16-u span. Zero barriers in seq (intra-wave shfl broadcast).
__global__ __launch_bounds__(256, 1)
void fused(const short* __restrict__ Xbf, const short* __restrict__ Wbf,
           const float* __restrict__ Wf, const float* __restrict__ bias,
           float* __restrict__ out)
{
    __shared__ __align__(16) short Hs[RB * HCOLS];       // 73,728 B
    __shared__ __align__(16) char  Ub[128 * LWR * 4];    // 81,920 B union

    short* xs   = (short*)Ub;                 // [32][TS]   8,704 B
    short* Wst  = (short*)(Ub + RB * TS * 2); // [128][TS] ends 43,520
    float* PreL = (float*)(Ub + 43520);       // [32][PLS] ends 60,416
    float* lwf  = (float*)Ub;                 // [128][LWR] seq phase

    const int tid  = threadIdx.x;
    const int lane = tid & 63;
    const int w    = tid >> 6;       // wave 0..3
    const int rl   = lane & 31;      // GEMM fragment row/col
    const int hf   = lane >> 5;      // GEMM k-half
    const int r8   = lane & 7;       // seq: row within wave's 8
    const int sl   = lane >> 3;      // seq: slice 0..7 (16 u's)
    const int rW   = w * 8 + r8;     // seq row within block
    const int u_lo = sl * 16;
    const int ucol = sl * 20;        // swizzled lwf column base
    const int bm   = blockIdx.x * RB;

#pragma unroll 1
    for (int J = 0; J < NJ; ++J) {
        const int j0 = J * 128;
        f32x16 acc;
#pragma unroll
        for (int r = 0; r < 16; ++r) acc[r] = 0.f;

        __syncthreads();   // prev seq (Hs writes, lwf reads) complete

        // ---- GEMM phase 1: k in [0,1024), A from Xbf staged ---------------
#pragma unroll 1
        for (int k0 = 0; k0 < IN_DIM; k0 += 128) {
#pragma unroll
            for (int c = 0; c < 2; ++c) {
                int idx = tid + c * 256;
                int r = idx >> 4, k8 = (idx & 15) << 3;
                *(short8*)&xs[r * TS + k8] =
                    *(const short8*)(Xbf + (size_t)(bm + r) * IN_DIM + k0 + k8);
            }
#pragma unroll
            for (int c = 0; c < 8; ++c) {
                int idx = tid + c * 256;
                int n = idx >> 4, k8 = (idx & 15) << 3;
                *(short8*)&Wst[n * TS + k8] =
                    *(const short8*)(Wbf + (size_t)(j0 + n) * P_DIM + k0 + k8);
            }
            __syncthreads();
#pragma unroll
            for (int k16 = 0; k16 < 8; ++k16) {
                short8 a = *(const short8*)&xs[rl * TS + k16 * 16 + hf * 8];
                short8 b = *(const short8*)&Wst[(w * 32 + rl) * TS + k16 * 16 + hf * 8];
                acc = __builtin_amdgcn_mfma_f32_32x32x16_bf16(a, b, acc, 0, 0, 0);
            }
            __syncthreads();
        }

        // ---- GEMM phase 2: k in [1024,1024+j0), A from H panel ------------
#pragma unroll 1
        for (int k0 = 0; k0 < j0; k0 += 128) {
#pragma unroll
            for (int c = 0; c < 8; ++c) {
                int idx = tid + c * 256;
                int n = idx >> 4, k8 = (idx & 15) << 3;
                *(short8*)&Wst[n * TS + k8] =
                    *(const short8*)(Wbf + (size_t)(j0 + n) * P_DIM + IN_DIM + k0 + k8);
            }
            __syncthreads();
#pragma unroll
            for (int k16 = 0; k16 < 8; ++k16) {
                short8 a = *(const short8*)&Hs[rl * HCOLS + k0 + k16 * 16 + hf * 8];
                short8 b = *(const short8*)&Wst[(w * 32 + rl) * TS + k16 * 16 + hf * 8];
                acc = __builtin_amdgcn_mfma_f32_32x32x16_bf16(a, b, acc, 0, 0, 0);
            }
            __syncthreads();
        }

        // ---- epilogue: PreL[row][col] = acc + bias ------------------------
        {
            float bv = bias[j0 + w * 32 + rl];
#pragma unroll
            for (int r = 0; r < 16; ++r) {
                int row = (r & 3) + 8 * (r >> 2) + 4 * hf;
                PreL[row * PLS + w * 32 + rl] = acc[r] + bv;
            }
        }
        __syncthreads();

        float as[16];
#pragma unroll
        for (int q = 0; q < 4; ++q) {
            float4 v = *(const float4*)&PreL[rW * PLS + u_lo + q * 4];
            as[q * 4 + 0] = v.x; as[q * 4 + 1] = v.y;
            as[q * 4 + 2] = v.z; as[q * 4 + 3] = v.w;
        }
        __syncthreads();

        // ---- stage LW f32, triangular-zeroed, slice-swizzled cols ---------
        {
            int u = tid & 127, th = tid >> 7;
            int uc = (u >> 4) * 20 + (u & 15);
#pragma unroll
            for (int it = 0; it < 16; ++it) {
                int t4 = (it * 2 + th) * 4;
                float4 v = *(const float4*)(Wf + (size_t)(j0 + u) * P_DIM + IN_DIM + j0 + t4);
                lwf[(t4 + 0) * LWR + uc] = (u > t4 + 0) ? v.x : 0.f;
                lwf[(t4 + 1) * LWR + uc] = (u > t4 + 1) ? v.y : 0.f;
                lwf[(t4 + 2) * LWR + uc] = (u > t4 + 2) ? v.z : 0.f;
                lwf[(t4 + 3) * LWR + uc] = (u > t4 + 3) ? v.w : 0.f;
            }
        }
        __syncthreads();

        // ---- 128 sequential steps, barrier-free (intra-wave only) ---------
#pragma unroll 1
        for (int g = 0; g < 8; ++g) {
            const bool own = (sl == g);
            const int src = r8 | (g << 3);
#pragma unroll
            for (int s = 0; s < 16; ++s) {
                const int t = g * 16 + s;
                const float* wr_ = &lwf[t * LWR + ucol];
                float4 w0 = *(const float4*)(wr_ + 0);
                float4 w1 = *(const float4*)(wr_ + 4);
                float4 w2 = *(const float4*)(wr_ + 8);
                float4 w3 = *(const float4*)(wr_ + 12);
                float th_ = tanh_fast(as[s]);
                float h = __shfl(th_, src);
                if (own) as[s] = th_;
                as[0]  += w0.x * h; as[1]  += w0.y * h;
                as[2]  += w0.z * h; as[3]  += w0.w * h;
                as[4]  += w1.x * h; as[5]  += w1.y * h;
                as[6]  += w1.z * h; as[7]  += w1.w * h;
                as[8]  += w2.x * h; as[9]  += w2.y * h;
                as[10] += w2.z * h; as[11] += w2.w * h;
                as[12] += w3.x * h; as[13] += w3.y * h;
                as[14] += w3.z * h; as[15] += w3.w * h;
            }
        }

        // ---- write h to H panel (skip J=9: never re-read) -----------------
        if (J < 9) {
#pragma unroll
            for (int q = 0; q < 2; ++q) {
                short8 sv;
#pragma unroll
                for (int e = 0; e < 8; ++e) sv[e] = f2bf(as[q * 8 + e]);
                *(short8*)&Hs[rW * HCOLS + j0 + u_lo + q * 8] = sv;
            }
        }

        // ---- output region ------------------------------------------------
        if (J >= 8) {
            float* op = out + (size_t)(bm + rW) * OUT_DIM + (j0 - IN_DIM) + u_lo;
#pragma unroll
            for (int q = 0; q < 4; ++q) {
                float4 v;
                v.x = 1.f / (1.f + __expf(-as[q * 4 + 0]));
                v.y = 1.f / (1.f + __expf(-as[q * 4 + 1]));
                v.z = 1.f / (1.f + __expf(-as[q * 4 + 2]));
                v.w = 1.f / (1.f + __expf(-as[q * 4 + 3]));
                *(float4*)(op + q * 4) = v;
            }
        }
    }
}

extern "C" void kernel_launch(void* const* d_in, const int* in_sizes, int n_in,
                              void* d_out, int out_size, void* d_ws, size_t ws_size,
                              hipStream_t stream)
{
    const float* x    = (const float*)d_in[0];
    const float* W    = (const float*)d_in[1];
    const float* bias = (const float*)d_in[2];
    float* out = (float*)d_out;
    short* Xbf = (short*)d_ws;
    short* Wbf = (short*)((char*)d_ws + WBF_OFF);

    convert_x<<<dim3(B_ROWS * IN_DIM / 8 / 256), dim3(256), 0, stream>>>(x, Xbf);
    convert_w<<<dim3(M_DIM * P_DIM / 8 / 256), dim3(256), 0, stream>>>(W, Wbf);
    fused<<<dim3(B_ROWS / RB), dim3(256), 0, stream>>>(Xbf, Wbf, W, bias, out);
}

// Round 10
// 314.047 us; speedup vs baseline: 2.1593x; 2.1224x over previous
//
#include <hip/hip_runtime.h>
#include <hip/hip_bf16.h>
#include <math.h>

typedef short short8 __attribute__((ext_vector_type(8)));
typedef float f32x4  __attribute__((ext_vector_type(4)));
typedef unsigned int u32;

#define B_ROWS 8192
#define IN_DIM 1024
#define OUT_DIM 256
#define M_DIM 1280
#define P_DIM 2304
#define NJ 10
#define RB 16                  // batch rows per block -> 512 blocks, 2 blocks/CU
#define BK 64                  // k per tile
#define HG_COLS 1152

// ws: Xbf bf16[8192][1024] @0 ; Wbf bf16[1280][2304] ; Hg bf16[8192][1152]
#define WBF_OFF (B_ROWS * (size_t)IN_DIM * 2)                 // 16,777,216
#define HG_OFF  (WBF_OFF + (size_t)M_DIM * P_DIM * 2)         // 22,675,456 (end 41,549,824)

__device__ __forceinline__ short f2bf(float x)
{
    __hip_bfloat16 h = __float2bfloat16(x);
    return *(short*)&h;
}

__device__ __forceinline__ float tanh_fast(float x)
{
    x = fminf(fmaxf(x, -15.f), 15.f);
    float e = __expf(2.f * x);
    return (e - 1.f) * __builtin_amdgcn_rcpf(e + 1.f);
}

__global__ __launch_bounds__(256)
void convert_x(const float* __restrict__ x, short* __restrict__ Xbf)
{
    int idx = blockIdx.x * 256 + threadIdx.x;
    int r  = idx >> 7;
    int c8 = (idx & 127) << 3;
    const float* src = x + (size_t)r * IN_DIM + c8;
    float4 a0 = *(const float4*)src;
    float4 a1 = *(const float4*)(src + 4);
    short8 s;
    s[0] = f2bf(a0.x); s[1] = f2bf(a0.y); s[2] = f2bf(a0.z); s[3] = f2bf(a0.w);
    s[4] = f2bf(a1.x); s[5] = f2bf(a1.y); s[6] = f2bf(a1.z); s[7] = f2bf(a1.w);
    *(short8*)(Xbf + (size_t)r * IN_DIM + c8) = s;
}

__global__ __launch_bounds__(256)
void convert_w(const float* __restrict__ W, short* __restrict__ Wbf)
{
    size_t e8 = ((size_t)blockIdx.x * 256 + threadIdx.x) * 8;
    float4 a0 = *(const float4*)(W + e8);
    float4 a1 = *(const float4*)(W + e8 + 4);
    short8 s;
    s[0] = f2bf(a0.x); s[1] = f2bf(a0.y); s[2] = f2bf(a0.z); s[3] = f2bf(a0.w);
    s[4] = f2bf(a1.x); s[5] = f2bf(a1.y); s[6] = f2bf(a1.z); s[7] = f2bf(a1.w);
    *(short8*)(Wbf + e8) = s;
}

// LDS layout (43,264 B union):
//  GEMM: xs[2] @0/@2048 (16x64 bf16, 128B rows, XOR-swz) ; Wst[2] @4096/@20480 (128x64)
//  seq : PreL f32[16][132] @0 (8,448) ; lwf bf16[128][136] @8448 (34,816)
#define LWF_OFF 8448
#define PLS 132
#define LWS 136

__global__ __launch_bounds__(256, 2)
void fused(const short* __restrict__ Xbf, const short* __restrict__ Wbf,
           short* __restrict__ Hg, const float* __restrict__ bias,
           float* __restrict__ out)
{
    __shared__ __align__(16) char L[43264];

    const int tid  = threadIdx.x;
    const int lane = tid & 63;
    const int w    = tid >> 6;      // wave 0..3
    const int fr   = lane & 15;     // fragment row/col
    const int fq   = lane >> 4;     // k-quarter / row-quad
    const int r4   = lane & 3;      // seq: row within wave's 4
    const int sl   = lane >> 2;     // seq: slice 0..15 (8 u's)
    const int srow = w * 4 + r4;    // seq row in block
    const int bm   = blockIdx.x * RB;

    // staging index precompute
    const int sa_r  = tid >> 3;         // A: row (tid<128)
    const int sa_k8 = (tid & 7) << 3;   // A: k offset

#pragma unroll 1
    for (int J = 0; J < NJ; ++J) {
        const int j0 = J * 128;
        const int nt = (IN_DIM + j0) / BK;

        f32x4 acc0 = {0.f, 0.f, 0.f, 0.f};
        f32x4 acc1 = {0.f, 0.f, 0.f, 0.f};

        short8 ra; short8 rw[4];
        // ---- load tile 0 into regs ----
        {
            if (tid < 128)
                ra = *(const short8*)(Xbf + (size_t)(bm + sa_r) * IN_DIM + sa_k8);
#pragma unroll
            for (int c = 0; c < 4; ++c) {
                int idx = tid + c * 256;
                int n = idx >> 3, k8 = (idx & 7) << 3;
                rw[c] = *(const short8*)(Wbf + (size_t)(j0 + n) * P_DIM + k8);
            }
        }
        // write tile 0 to buf0 (XOR-swizzled)
        {
            if (tid < 128)
                *(short8*)(L + ((sa_r * 128 + sa_k8 * 2) ^ ((sa_r & 7) << 4))) = ra;
#pragma unroll
            for (int c = 0; c < 4; ++c) {
                int idx = tid + c * 256;
                int n = idx >> 3, k8 = (idx & 7) << 3;
                *(short8*)(L + 4096 + ((n * 128 + k8 * 2) ^ ((n & 7) << 4))) = rw[c];
            }
        }

#pragma unroll 1
        for (int t = 0; t < nt; ++t) {
            // issue next tile's global loads (overlap with MFMA below)
            if (t + 1 < nt) {
                int k0 = (t + 1) * BK;
                if (tid < 128) {
                    const short* src = (k0 < IN_DIM)
                        ? (Xbf + (size_t)(bm + sa_r) * IN_DIM + k0 + sa_k8)
                        : (Hg + (size_t)(bm + sa_r) * HG_COLS + (k0 - IN_DIM) + sa_k8);
                    ra = *(const short8*)src;
                }
#pragma unroll
                for (int c = 0; c < 4; ++c) {
                    int idx = tid + c * 256;
                    int n = idx >> 3, k8 = (idx & 7) << 3;
                    rw[c] = *(const short8*)(Wbf + (size_t)(j0 + n) * P_DIM + k0 + k8);
                }
            }
            __syncthreads();   // buf[t&1] writes visible
            const char* xb = L + (t & 1) * 2048;
            const char* wb = L + 4096 + (t & 1) * 16384;
            const int n0 = w * 32 + fr;
            const int n1 = n0 + 16;
#pragma unroll
            for (int k32 = 0; k32 < 2; ++k32) {
                int kb = k32 * 64 + fq * 16;
                short8 a  = *(const short8*)(xb + ((fr * 128 + kb) ^ ((fr & 7) << 4)));
                short8 b0 = *(const short8*)(wb + ((n0 * 128 + kb) ^ ((n0 & 7) << 4)));
                short8 b1 = *(const short8*)(wb + ((n1 * 128 + kb) ^ ((n1 & 7) << 4)));
                acc0 = __builtin_amdgcn_mfma_f32_16x16x32_bf16(a, b0, acc0, 0, 0, 0);
                acc1 = __builtin_amdgcn_mfma_f32_16x16x32_bf16(a, b1, acc1, 0, 0, 0);
            }
            // write prefetched tile to the other buffer (safe: different buf)
            if (t + 1 < nt) {
                char* xw = L + ((t + 1) & 1) * 2048;
                char* ww = L + 4096 + ((t + 1) & 1) * 16384;
                if (tid < 128)
                    *(short8*)(xw + ((sa_r * 128 + sa_k8 * 2) ^ ((sa_r & 7) << 4))) = ra;
#pragma unroll
                for (int c = 0; c < 4; ++c) {
                    int idx = tid + c * 256;
                    int n = idx >> 3, k8 = (idx & 7) << 3;
                    *(short8*)(ww + ((n * 128 + k8 * 2) ^ ((n & 7) << 4))) = rw[c];
                }
            }
        }
        __syncthreads();   // all MFMAs done; LDS free for seq-phase overlay

        // ---- epilogue: PreL = acc + bias; stage lwf (bf16, tri-zeroed) ----
        {
            float* PreL = (float*)L;
            float bv0 = bias[j0 + w * 32 + fr];
            float bv1 = bias[j0 + w * 32 + 16 + fr];
#pragma unroll
            for (int r = 0; r < 4; ++r) {
                PreL[(fq * 4 + r) * PLS + w * 32 + fr]      = acc0[r] + bv0;
                PreL[(fq * 4 + r) * PLS + w * 32 + 16 + fr] = acc1[r] + bv1;
            }
            short* lwf = (short*)(L + LWF_OFF);
            int u = tid & 127, th = tid >> 7;
            const short* wr_ = Wbf + (size_t)(j0 + u) * P_DIM + IN_DIM + j0 + th * 64;
#pragma unroll
            for (int s8 = 0; s8 < 8; ++s8) {
                short8 v = *(const short8*)(wr_ + s8 * 8);
#pragma unroll
                for (int e = 0; e < 8; ++e) {
                    int tt = th * 64 + s8 * 8 + e;
                    lwf[tt * LWS + u] = (u > tt) ? v[e] : (short)0;
                }
            }
        }
        __syncthreads();

        // ---- read PreL into seq registers ----
        float as[8];
        {
            const float* pr = (const float*)L + srow * PLS + sl * 8;
            f32x4 v0 = *(const f32x4*)pr;
            f32x4 v1 = *(const f32x4*)(pr + 4);
            as[0] = v0[0]; as[1] = v0[1]; as[2] = v0[2]; as[3] = v0[3];
            as[4] = v1[0]; as[5] = v1[1]; as[6] = v1[2]; as[7] = v1[3];
        }

        // ---- 128 sequential steps; 1 ds_read + 1 shfl per step ----
        const short* lwf = (const short*)(L + LWF_OFF);
#pragma unroll 1
        for (int g = 0; g < 16; ++g) {
            const int hsrc = r4 | (g << 2);
            const bool own = (sl == g);
#pragma unroll
            for (int s = 0; s < 8; ++s) {
                const int t = g * 8 + s;
                short8 wv = *(const short8*)(lwf + t * LWS + sl * 8);
                float th_ = tanh_fast(as[s]);
                float h = __shfl(th_, hsrc);
                if (own) as[s] = th_;
#pragma unroll
                for (int e = 0; e < 8; ++e) {
                    float wf = __uint_as_float(((u32)(unsigned short)wv[e]) << 16);
                    as[e] += wf * h;
                }
            }
        }

        // ---- write h to global H panel / output ----
        if (J < 9) {
            short8 hv;
#pragma unroll
            for (int e = 0; e < 8; ++e) hv[e] = f2bf(as[e]);
            *(short8*)(Hg + (size_t)(bm + srow) * HG_COLS + j0 + sl * 8) = hv;
        }
        if (J >= 8) {
            float* op = out + (size_t)(bm + srow) * OUT_DIM + (j0 - IN_DIM) + sl * 8;
            float4 o0, o1;
            o0.x = 1.f / (1.f + __expf(-as[0]));
            o0.y = 1.f / (1.f + __expf(-as[1]));
            o0.z = 1.f / (1.f + __expf(-as[2]));
            o0.w = 1.f / (1.f + __expf(-as[3]));
            o1.x = 1.f / (1.f + __expf(-as[4]));
            o1.y = 1.f / (1.f + __expf(-as[5]));
            o1.z = 1.f / (1.f + __expf(-as[6]));
            o1.w = 1.f / (1.f + __expf(-as[7]));
            *(float4*)op = o0;
            *(float4*)(op + 4) = o1;
        }
        __syncthreads();   // protect lwf/PreL from next J's staging
    }
}

extern "C" void kernel_launch(void* const* d_in, const int* in_sizes, int n_in,
                              void* d_out, int out_size, void* d_ws, size_t ws_size,
                              hipStream_t stream)
{
    const float* x    = (const float*)d_in[0];
    const float* W    = (const float*)d_in[1];
    const float* bias = (const float*)d_in[2];
    float* out = (float*)d_out;
    short* Xbf = (short*)d_ws;
    short* Wbf = (short*)((char*)d_ws + WBF_OFF);
    short* Hg  = (short*)((char*)d_ws + HG_OFF);

    convert_x<<<dim3(B_ROWS * IN_DIM / 8 / 256), dim3(256), 0, stream>>>(x, Xbf);
    convert_w<<<dim3(M_DIM * P_DIM / 8 / 256), dim3(256), 0, stream>>>(W, Wbf);
    fused<<<dim3(B_ROWS / RB), dim3(256), 0, stream>>>(Xbf, Wbf, Hg, bias, out);
}